// Round 4
// baseline (15258.519 us; speedup 1.0000x reference)
//
#include <hip/hip_runtime.h>
#include <hip/hip_cooperative_groups.h>
#include <cmath>

namespace cg = cooperative_groups;

#define IN_DIM 1024
#define HD 256
#define G4H 1024
#define BB 64
#define TT 512
#define NCLS 8

/* h rings: 3 layers x 16 slots x [k(=j)][b] */
#define RING 16
#define SLOT_STRIDE (HD * BB)             /* 16384 floats */
#define LAYER_STRIDE (RING * SLOT_STRIDE) /* 262144 floats */

__device__ __forceinline__ float sigmoidf_(float x) {
    return 1.0f / (1.0f + __expf(-x));
}
__device__ __forceinline__ float tanhf_(float x) {
    return 2.0f / (1.0f + __expf(-2.0f * x)) - 1.0f;
}
__device__ __forceinline__ float ld_agent(const float* p) {
    return __hip_atomic_load(p, __ATOMIC_RELAXED, __HIP_MEMORY_SCOPE_AGENT);
}
__device__ __forceinline__ void st_agent(float* p, float v) {
    __hip_atomic_store(p, v, __ATOMIC_RELAXED, __HIP_MEMORY_SCOPE_AGENT);
}
__device__ __forceinline__ int ld_flag(const int* p) {
    return __hip_atomic_load(p, __ATOMIC_RELAXED, __HIP_MEMORY_SCOPE_AGENT);
}
__device__ __forceinline__ void st_flag(int* p, int v) {
    __hip_atomic_store(p, v, __ATOMIC_RELAXED, __HIP_MEMORY_SCOPE_AGENT);
}

/* ---------------- Kernel 1: xgT[t][n/4][b][4] = (x @ Wih0^T + b0) transposed ---------------- */
#define GBM 128
#define GBN 128
#define GBK 16

__global__ __launch_bounds__(256) void xg0_gemm(const float* __restrict__ x,
                                                const float* __restrict__ Wih0,
                                                const float* __restrict__ b0,
                                                float* __restrict__ xgT) {
    __shared__ float As[GBK][GBM];
    __shared__ float Bs[GBK][GBN];
    const int m0 = blockIdx.y * GBM;
    const int n0 = blockIdx.x * GBN;
    const int tid = threadIdx.x;
    const int tx = tid & 15;
    const int ty = tid >> 4;
    const int lr = tid >> 1;
    const int lk = (tid & 1) * 8;
    float acc[8][8] = {};
    for (int k0 = 0; k0 < IN_DIM; k0 += GBK) {
        const float4 a0 = *(const float4*)&x[(size_t)(m0 + lr) * IN_DIM + k0 + lk];
        const float4 a1 = *(const float4*)&x[(size_t)(m0 + lr) * IN_DIM + k0 + lk + 4];
        const float4 w0 = *(const float4*)&Wih0[(size_t)(n0 + lr) * IN_DIM + k0 + lk];
        const float4 w1 = *(const float4*)&Wih0[(size_t)(n0 + lr) * IN_DIM + k0 + lk + 4];
        __syncthreads();
        As[lk + 0][lr] = a0.x; As[lk + 1][lr] = a0.y; As[lk + 2][lr] = a0.z; As[lk + 3][lr] = a0.w;
        As[lk + 4][lr] = a1.x; As[lk + 5][lr] = a1.y; As[lk + 6][lr] = a1.z; As[lk + 7][lr] = a1.w;
        Bs[lk + 0][lr] = w0.x; Bs[lk + 1][lr] = w0.y; Bs[lk + 2][lr] = w0.z; Bs[lk + 3][lr] = w0.w;
        Bs[lk + 4][lr] = w1.x; Bs[lk + 5][lr] = w1.y; Bs[lk + 6][lr] = w1.z; Bs[lk + 7][lr] = w1.w;
        __syncthreads();
#pragma unroll
        for (int k = 0; k < GBK; ++k) {
            const float4 av0 = *(const float4*)&As[k][ty * 8];
            const float4 av1 = *(const float4*)&As[k][ty * 8 + 4];
            const float4 bv0 = *(const float4*)&Bs[k][tx * 8];
            const float4 bv1 = *(const float4*)&Bs[k][tx * 8 + 4];
            const float am[8] = {av0.x, av0.y, av0.z, av0.w, av1.x, av1.y, av1.z, av1.w};
            const float bn[8] = {bv0.x, bv0.y, bv0.z, bv0.w, bv1.x, bv1.y, bv1.z, bv1.w};
#pragma unroll
            for (int i = 0; i < 8; ++i)
#pragma unroll
                for (int jj = 0; jj < 8; ++jj)
                    acc[i][jj] = fmaf(am[i], bn[jj], acc[i][jj]);
        }
    }
    const float4 bias0 = *(const float4*)&b0[n0 + tx * 8];
    const float4 bias1 = *(const float4*)&b0[n0 + tx * 8 + 4];
    const int nq0 = (n0 >> 2) + tx * 2;
#pragma unroll
    for (int i = 0; i < 8; ++i) {
        const int m = m0 + ty * 8 + i;
        const int b = m >> 9;       // x row = b*T + t
        const int t = m & 511;
        float4 v0, v1;
        v0.x = acc[i][0] + bias0.x; v0.y = acc[i][1] + bias0.y;
        v0.z = acc[i][2] + bias0.z; v0.w = acc[i][3] + bias0.w;
        v1.x = acc[i][4] + bias1.x; v1.y = acc[i][5] + bias1.y;
        v1.z = acc[i][6] + bias1.z; v1.w = acc[i][7] + bias1.w;
        float* p = xgT + (size_t)(t * 256 + nq0) * 256 + b * 4;
        *(float4*)p = v0;
        *(float4*)(p + 256) = v1;
    }
}

/* ---------------- Kernel 2: 3-stage flag-synced LSTM ----------------
 * 192 blocks = 3 layers x 64 blocks; 512 threads = 8 waves. Block owns 4 j (16 gate
 * rows) x 64 b. Wave w = k-chunk [32w,32w+32) partials for all 16 rows (lane=b).
 * Monotonic per-block tick flags (one 256B line per layer). ih partial for t computed
 * BEFORE polling siblings for h[t-1] (hides flag propagation). 16-deep ring, consumer
 * progress published every 8 ticks. */
__device__ __forceinline__ void mat_partial(const float* __restrict__ W,
                                            const float* __restrict__ hslot,
                                            int jbase, int kbase, int b, float* acc) {
    float hv[32];
#pragma unroll
    for (int u = 0; u < 32; ++u) hv[u] = ld_agent(&hslot[(kbase + u) * BB + b]);
#pragma unroll
    for (int kk = 0; kk < 32; kk += 4) {
#pragma unroll
        for (int jl = 0; jl < 4; ++jl)
#pragma unroll
            for (int g = 0; g < 4; ++g) {
                const float4 wv = *(const float4*)&W[(size_t)(g * HD + jbase + jl) * HD + kbase + kk];
                float a = acc[jl * 4 + g];
                a = fmaf(wv.x, hv[kk + 0], a); a = fmaf(wv.y, hv[kk + 1], a);
                a = fmaf(wv.z, hv[kk + 2], a); a = fmaf(wv.w, hv[kk + 3], a);
                acc[jl * 4 + g] = a;
            }
    }
}

__global__ __launch_bounds__(512, 2) void lstm_cells(
    const float* __restrict__ xgT,
    const float* __restrict__ Whh0,
    const float* __restrict__ Wih1, const float* __restrict__ Whh1, const float* __restrict__ b1,
    const float* __restrict__ Wih2, const float* __restrict__ Whh2, const float* __restrict__ b2,
    float* __restrict__ hring, int* __restrict__ prog, int* __restrict__ consp)
{
    cg::grid_group grid = cg::this_grid();
    const int blk = blockIdx.x;
    const int layer = blk >> 6;        // 0..2
    const int lb = blk & 63;
    const int jbase = lb * 4;
    const int tid = threadIdx.x;
    const int w = tid >> 6;            // wave 0..7; k-chunk [32w, 32w+32)
    const int b = tid & 63;
    const int kbase = w * 32;

    __shared__ float red[16 * 8 * 64]; // [row][wave][b] = 32 KB
    __shared__ float xs[4 * 4 * 64];   // [g][jl][b] = 4 KB (layer 0)

    const float* Wih = (layer == 1) ? Wih1 : Wih2;
    const float* Whh = (layer == 0) ? Whh0 : ((layer == 1) ? Whh1 : Whh2);
    const float* bias = (layer == 1) ? b1 : b2;

    // zero flags (ws is poisoned); rings need no zeroing (t=0 skips h[t-1])
    for (int i = blk * 512 + tid; i < 3 * 64 + 2 * 64; i += 192 * 512) {
        if (i < 192) prog[i] = 0; else consp[i - 192] = 0;
    }

    float bs0 = 0.f, bs1 = 0.f, bs2 = 0.f, bs3 = 0.f;
    if (layer > 0 && w < 4) {
        bs0 = bias[0 * HD + jbase + w]; bs1 = bias[1 * HD + jbase + w];
        bs2 = bias[2 * HD + jbase + w]; bs3 = bias[3 * HD + jbase + w];
    }

    float* myring = hring + layer * LAYER_STRIDE;
    const float* inring = hring + (layer - 1) * LAYER_STRIDE;
    int* prog_own = prog + layer * 64;
    const int* prog_in = prog + (layer - 1) * 64;

    float c = 0.0f;

    grid.sync();   // flags zeroed, visible device-wide

    for (int t = 0; t < TT; ++t) {
        /* ---- ring-reuse guard: every 8 ticks, producers check consumer progress ---- */
        if (layer < 2 && t >= RING && (t & 7) == 0) {
            if (tid < 64) {
                const int* cp = &consp[layer * 64 + tid];
                while (!__all(ld_flag(cp) >= t - 8)) __builtin_amdgcn_s_sleep(2);
            }
            __syncthreads();
        }

        float acc[16];
#pragma unroll
        for (int r = 0; r < 16; ++r) acc[r] = 0.0f;

        /* ---- phase 1: input contribution (no own-layer dependency) ---- */
        if (layer == 0) {
            if (w < 4) {   // wave g loads xgT[t][g*64+lb][b][0..3], coalesced 1KB
                const float4 v = *(const float4*)&xgT[(size_t)(t * 256 + w * 64 + lb) * 256 + b * 4];
                xs[(w * 4 + 0) * 64 + b] = v.x;
                xs[(w * 4 + 1) * 64 + b] = v.y;
                xs[(w * 4 + 2) * 64 + b] = v.z;
                xs[(w * 4 + 3) * 64 + b] = v.w;
            }
        } else {
            if (tid < 64) {   // wait for producer layer tick t complete
                const int* pi = &prog_in[tid];
                while (!__all(ld_flag(pi) >= t + 1)) __builtin_amdgcn_s_sleep(1);
            }
            __syncthreads();
            mat_partial(Wih, inring + (size_t)(t & (RING - 1)) * SLOT_STRIDE, jbase, kbase, b, acc);
        }

        /* ---- phase 2: own recurrence h[t-1] (sibling flags had time to propagate) ---- */
        if (t > 0) {
            if (tid < 64) {
                const int* po = &prog_own[tid];
                while (!__all(ld_flag(po) >= t)) __builtin_amdgcn_s_sleep(1);
            }
            __syncthreads();
            mat_partial(Whh, myring + (size_t)((t - 1) & (RING - 1)) * SLOT_STRIDE, jbase, kbase, b, acc);
        }

        /* ---- cross-wave reduction ---- */
#pragma unroll
        for (int r = 0; r < 16; ++r) red[(r * 8 + w) * 64 + b] = acc[r];
        __syncthreads();

        /* ---- cell update on waves 0..3 (jl = w) ---- */
        if (w < 4) {
            float a0, a1, a2, a3;
            if (layer == 0) {
                a0 = xs[(0 * 4 + w) * 64 + b]; a1 = xs[(1 * 4 + w) * 64 + b];
                a2 = xs[(2 * 4 + w) * 64 + b]; a3 = xs[(3 * 4 + w) * 64 + b];
            } else {
                a0 = bs0; a1 = bs1; a2 = bs2; a3 = bs3;
            }
#pragma unroll
            for (int ww = 0; ww < 8; ++ww) {
                a0 += red[((w * 4 + 0) * 8 + ww) * 64 + b];
                a1 += red[((w * 4 + 1) * 8 + ww) * 64 + b];
                a2 += red[((w * 4 + 2) * 8 + ww) * 64 + b];
                a3 += red[((w * 4 + 3) * 8 + ww) * 64 + b];
            }
            const float ig = sigmoidf_(a0);
            const float fg = sigmoidf_(a1);
            const float gg = tanhf_(a2);
            const float og = sigmoidf_(a3);
            c = fg * c + ig * gg;
            const float h = og * tanhf_(c);
            st_agent(&myring[(size_t)(t & (RING - 1)) * SLOT_STRIDE + (size_t)(jbase + w) * BB + b], h);
        }

        __syncthreads();   // barrier waitcnt drains the h stores to LLC
        if (tid == 0) {
            st_flag(&prog_own[lb], t + 1);
            if (layer > 0 && (t & 7) == 7)
                st_flag(&consp[(layer - 1) * 64 + lb], t + 1);
        }
    }
}

/* ---------------- Kernel 3: FC head on h2[T-1] ([k][b] layout) ---------------- */
__global__ __launch_bounds__(256) void classifier_k(
    const float* __restrict__ hring,
    const float* __restrict__ W1, const float* __restrict__ bfc1,
    const float* __restrict__ W2, const float* __restrict__ bfc2,
    float* __restrict__ out)
{
    __shared__ float z[BB * 128];
    const float* h2T = hring + 2 * LAYER_STRIDE + (size_t)((TT - 1) & (RING - 1)) * SLOT_STRIDE;
    const int tid = threadIdx.x;
    for (int idx = tid; idx < BB * 128; idx += 256) {
        const int bb = idx >> 7;
        const int n = idx & 127;
        float acc = bfc1[n];
        const float* wr = W1 + (size_t)n * HD;
        for (int k = 0; k < HD; ++k)
            acc = fmaf(h2T[k * BB + bb], wr[k], acc);
        z[bb * 128 + n] = fmaxf(acc, 0.0f);
    }
    __syncthreads();
    for (int idx = tid; idx < BB * NCLS; idx += 256) {
        const int bb = idx >> 3;
        const int n = idx & 7;
        float acc = bfc2[n];
        const float* zr = &z[bb * 128];
        const float* wr = W2 + (size_t)n * 128;
        for (int k = 0; k < 128; k += 4) {
            const float4 zv = *(const float4*)&zr[k];
            const float4 wv = *(const float4*)&wr[k];
            acc = fmaf(zv.x, wv.x, acc); acc = fmaf(zv.y, wv.y, acc);
            acc = fmaf(zv.z, wv.z, acc); acc = fmaf(zv.w, wv.w, acc);
        }
        out[idx] = acc;
    }
}

extern "C" void kernel_launch(void* const* d_in, const int* in_sizes, int n_in,
                              void* d_out, int out_size, void* d_ws, size_t ws_size,
                              hipStream_t stream) {
    const float* x    = (const float*)d_in[0];
    const float* Wih0 = (const float*)d_in[1];
    const float* Whh0 = (const float*)d_in[2];
    const float* b0   = (const float*)d_in[3];
    const float* Wih1 = (const float*)d_in[4];
    const float* Whh1 = (const float*)d_in[5];
    const float* b1   = (const float*)d_in[6];
    const float* Wih2 = (const float*)d_in[7];
    const float* Whh2 = (const float*)d_in[8];
    const float* b2   = (const float*)d_in[9];
    const float* W1   = (const float*)d_in[10];
    const float* bfc1 = (const float*)d_in[11];
    const float* W2   = (const float*)d_in[12];
    const float* bfc2 = (const float*)d_in[13];

    float* xgT   = (float*)d_ws;                       // T*4H*B fp32 = 134.2 MB
    float* hring = xgT + (size_t)TT * G4H * BB;        // 3*16*16384 fp32 = 3.1 MB
    int*   prog  = (int*)(hring + 3 * LAYER_STRIDE);   // 192 ints
    int*   consp = prog + 3 * 64;                      // 128 ints

    xg0_gemm<<<dim3(G4H / GBN, (BB * TT) / GBM), 256, 0, stream>>>(x, Wih0, b0, xgT);

    const float* xgc = xgT;
    float* hr = hring;
    int* pr = prog;
    int* cp = consp;
    void* args[] = {
        (void*)&xgc, (void*)&Whh0,
        (void*)&Wih1, (void*)&Whh1, (void*)&b1,
        (void*)&Wih2, (void*)&Whh2, (void*)&b2,
        (void*)&hr, (void*)&pr, (void*)&cp
    };
    hipLaunchCooperativeKernel((void*)lstm_cells, dim3(192), dim3(512), args, 0, stream);

    classifier_k<<<1, 256, 0, stream>>>(hring, W1, bfc1, W2, bfc2, (float*)d_out);
}